// Round 6
// baseline (302.813 us; speedup 1.0000x reference)
//
#include <hip/hip_runtime.h>
#include <math.h>

#define LSEQ   8192
#define CHUNK  64
#define NCHUNK 128
#define NBATCH 2048
#define NGRP   32      /* superchunks */
#define GLEN   4       /* chunks per superchunk: NGRP*GLEN == NCHUNK */

// ws float layout: E and SG live in the dead v-slot [0, T0); tables at T0+.
#define WS_E   0                            /* NBATCH*NGRP*64 = 4194304 floats */
#define WS_SG  (NBATCH * NGRP * 64)         /* same size; both fit in old v slot */
#define T0     (NBATCH * NCHUNK * 64)
#define WS_P   (T0)
#define WS_A1  (T0 + 4096)
#define WS_K   (T0 + 8192)
#define WS_WH  (T0 + 8256)    /* 4096 floats = 8192 bf16: W hi, row-major 128x64 */
#define WS_WL  (T0 + 12352)   /* 4096 floats: W lo */
#define WS_PH  (T0 + 16448)   /* 2048 floats = 4096 bf16: P hi, row-major 64x64 */
#define WS_PL  (T0 + 18496)
#define WS_A1H (T0 + 20544)
#define WS_A1L (T0 + 22592)
#define WS_PGH (T0 + 24640)   /* P^GLEN hi (boundary matrix for sg) */
#define WS_PGL (T0 + 26688)

typedef short bf16x8 __attribute__((ext_vector_type(8)));
typedef float f32x4  __attribute__((ext_vector_type(4)));
typedef unsigned short u16;

__device__ __forceinline__ u16 bf16rne(float x) {
  unsigned b = __builtin_bit_cast(unsigned, x);
  return (u16)((b + 0x7fffu + ((b >> 16) & 1u)) >> 16);
}
__device__ __forceinline__ float bf2f(u16 h) {
  return __builtin_bit_cast(float, ((unsigned)h) << 16);
}
__device__ __forceinline__ void split2(float x, u16& h, u16& l) {
  h = bf16rne(x);
  l = bf16rne(x - bf2f(h));
}
__device__ __forceinline__ void split3(float x, u16& h, u16& m, u16& l) {
  h = bf16rne(x);
  float r = x - bf2f(h);
  m = bf16rne(r);
  r -= bf2f(m);
  l = bf16rne(r);
}

// XOR swizzle on 8-col groups: kills the stride-128B same-bank pattern for
// ds_read_b128 fragment reads (G4/T2).
__device__ __forceinline__ int swz(int r, int c) {
  return r * 64 + (c ^ ((r & 7) << 3));
}
__device__ __forceinline__ float tri_get(const u16* p, int r, int c) {
  const int e = swz(r, c);
  return bf2f(p[e]) + bf2f(p[4096 + e]) + bf2f(p[8192 + e]);
}

// ---------------- pre: MFMA triple-bf16 64x64 matmuls (round-4, verified) ----
__device__ __forceinline__ void mfma_tile3(
    const u16* __restrict__ A3, const u16* __restrict__ B3, u16* __restrict__ D3,
    int mt, int nt, int aShift,
    const u16* add1, const u16* add2, int addI, int rLo, int rHi) {
  const int lane = threadIdx.x & 63;
  const int n = lane & 15, q = lane >> 4;
  int ar = mt * 16 + n - aShift;
  ar = ar < 0 ? 0 : (ar > 63 ? 63 : ar);
  const int bc = nt * 16 + n;
  bf16x8 ah[2], am[2], al[2], bh[2], bm[2], bl[2];
#pragma unroll
  for (int ks = 0; ks < 2; ++ks) {
    const int ao = swz(ar, ks * 32 + q * 8);
    const int bo = swz(bc, ks * 32 + q * 8);
    ah[ks] = *(const bf16x8*)(A3 + ao);
    am[ks] = *(const bf16x8*)(A3 + 4096 + ao);
    al[ks] = *(const bf16x8*)(A3 + 8192 + ao);
    bh[ks] = *(const bf16x8*)(B3 + bo);
    bm[ks] = *(const bf16x8*)(B3 + 4096 + bo);
    bl[ks] = *(const bf16x8*)(B3 + 8192 + bo);
  }
  f32x4 acc = {0.f, 0.f, 0.f, 0.f};
#define MF(a, b) acc = __builtin_amdgcn_mfma_f32_16x16x32_bf16(a, b, acc, 0, 0, 0)
  MF(ah[0], bh[0]); MF(ah[1], bh[1]);
  MF(ah[0], bm[0]); MF(ah[1], bm[1]);
  MF(am[0], bh[0]); MF(am[1], bh[1]);
  MF(ah[0], bl[0]); MF(ah[1], bl[1]);
  MF(am[0], bm[0]); MF(am[1], bm[1]);
  MF(al[0], bh[0]); MF(al[1], bh[1]);
#undef MF
#pragma unroll
  for (int j = 0; j < 4; ++j) {
    const int i = mt * 16 + q * 4 + j, c = nt * 16 + n;
    float v = acc[j];
    if (add1) v += tri_get(add1, i, c);
    if (add2) v += tri_get(add2, i, c);
    if (addI && i == c) v += 1.f;
    if (i >= rLo && i < rHi) {
      u16 h3, m3, l3; split3(v, h3, m3, l3);
      const int e = swz(i, c);
      D3[e] = h3; D3[4096 + e] = m3; D3[8192 + e] = l3;
    }
  }
}

__device__ __forceinline__ void pair_phase(
    const u16* Pf, const u16* Qt, u16* Fn, u16* Tn,
    const u16* addF1, const u16* addT1, int addI) {
  __syncthreads();
  const int w = threadIdx.x >> 6;
#pragma unroll
  for (int tix = w; tix < 32; tix += 16) {
    if (tix < 16) mfma_tile3(Pf, Qt, Fn, tix >> 2, tix & 3, 0, addF1, 0, addI, 0, 64);
    else { const int s = tix - 16; mfma_tile3(Qt, Pf, Tn, s >> 2, s & 3, 0, addT1, 0, addI, 0, 64); }
  }
}
__device__ __forceinline__ void single_phase(
    const u16* A3, const u16* B3, u16* D3,
    const u16* add1, const u16* add2, int addI) {
  __syncthreads();
  const int w = threadIdx.x >> 6;
  mfma_tile3(A3, B3, D3, w >> 2, w & 3, 0, add1, add2, addI, 0, 64);
}

__global__ void __launch_bounds__(1024)
ssm_pre(const float* __restrict__ Ag, const float* __restrict__ Bg,
        const float* __restrict__ Cg, const float* __restrict__ Dg,
        const float* __restrict__ lsg, float* __restrict__ ws) {
  __shared__ __attribute__((aligned(16))) u16 TRI[6][3 * 4096];
  __shared__ float Kl[64];
  u16* tri0 = TRI[0]; u16* tri1 = TRI[1]; u16* tri2 = TRI[2];
  u16* tri3 = TRI[3]; u16* tri4 = TRI[4]; u16* tri5 = TRI[5];

  const int t = threadIdx.x;
  const int w = t >> 6;
  const float step = expf(lsg[0]);
  const float hstep = 0.5f * step;
  const float D0 = Dg[0];

  float* Xf = (float*)tri2;
  for (int e = t; e < 4096; e += 1024) {
    const float x = hstep * Ag[e];
    Xf[e] = x;
    u16 h3, m3, l3; split3(x, h3, m3, l3);
    const int s = swz(e >> 6, e & 63);
    tri0[s] = h3; tri0[4096 + s] = m3; tri0[8192 + s] = l3;
  }
  __syncthreads();
  for (int e = t; e < 4096; e += 1024) {
    const int r = e >> 6, c = e & 63;
    const float x = Xf[c * 64 + r];
    u16 h3, m3, l3; split3(x, h3, m3, l3);
    const int s = swz(r, c);
    tri1[s] = h3; tri1[4096 + s] = m3; tri1[8192 + s] = l3;
  }
  pair_phase(tri0, tri1, tri2, tri3, 0, 0, 0);          // X2
  pair_phase(tri2, tri3, tri4, tri5, 0, 0, 0);          // X4
  single_phase(tri4, tri3, tri0, tri4, tri2, 1);        // T1
  single_phase(tri3, tri4, tri2, tri3, tri5, 1);        // T1T
  pair_phase(tri0, tri1, tri3, tri5, tri0, tri2, 0);    // BL / BLT
  pair_phase(tri3, tri1, tri4, tri2, tri3, tri5, 0);    // Ab / AbT

  __syncthreads();
  if (t < 64) {
    float acc = 0.f;
    for (int m = 0; m < 64; ++m) acc += tri_get(tri3, t, m) * Bg[m];  // BL row t
    const float bb = step * acc;
    u16 h3, m3, l3; split3(bb, h3, m3, l3);
    const int s = swz(0, t);
    tri0[s] = h3; tri0[4096 + s] = m3; tri0[8192 + s] = l3;
  } else if (t < 128) {
    const int r = t - 64;
    float acc = 0.f;
    for (int m = 0; m < 64; ++m) acc += tri_get(tri2, r, m) * Cg[m];  // AbT row r
    u16 h3, m3, l3; split3(acc, h3, m3, l3);
    const int s = swz(0, r);
    tri1[s] = h3; tri1[4096 + s] = m3; tri1[8192 + s] = l3;
  }

  u16 *curF = tri4, *curT = tri2, *nxtF = tri3, *nxtT = tri5;
  for (int k = 1; k <= 32; k <<= 1) {
    __syncthreads();
    const int mtLo = k >> 4, mtHi = (2 * k - 1) >> 4;
    const int cnt = (mtHi - mtLo + 1) * 4;
    const int total = 32 + 2 * cnt;
    for (int tix = w; tix < total; tix += 16) {
      if (tix < 16) {
        mfma_tile3(curF, curT, nxtF, tix >> 2, tix & 3, 0, 0, 0, 0, 0, 64);
      } else if (tix < 32) {
        const int s = tix - 16;
        mfma_tile3(curT, curF, nxtT, s >> 2, s & 3, 0, 0, 0, 0, 0, 64);
      } else if (tix < 32 + cnt) {
        const int s = tix - 32;
        mfma_tile3(tri0, curF, tri0, mtLo + (s >> 2), s & 3, k, 0, 0, 0, k, 2 * k);
      } else {
        const int s = tix - 32 - cnt;
        mfma_tile3(tri1, curT, tri1, mtLo + (s >> 2), s & 3, k, 0, 0, 0, k, 2 * k);
      }
    }
    u16* tmp;
    tmp = curF; curF = nxtF; nxtF = tmp;
    tmp = curT; curT = nxtT; nxtT = tmp;
  }

  __syncthreads();
  float* wsP  = ws + WS_P;
  float* wsA1 = ws + WS_A1;
  u16* ph  = (u16*)(ws + WS_PH);
  u16* pl  = (u16*)(ws + WS_PL);
  u16* a1h = (u16*)(ws + WS_A1H);
  u16* a1l = (u16*)(ws + WS_A1L);
  u16* pgh = (u16*)(ws + WS_PGH);
  u16* pgl = (u16*)(ws + WS_PGL);
  for (int e = t; e < 4096; e += 1024) {
    const float x = tri_get(curF, e >> 6, e & 63);
    wsP[e] = x;
    u16 hh, ll; split2(x, hh, ll); ph[e] = hh; pl[e] = ll;
  }
  // tail: P^2, P^4 = P^GLEN (GLEN==4) — two pair squarings
  for (int r2 = 0; r2 < 2; ++r2) {
    pair_phase(curF, curT, nxtF, nxtT, 0, 0, 0);
    u16* tmp;
    tmp = curF; curF = nxtF; nxtF = tmp;
    tmp = curT; curT = nxtT; nxtT = tmp;
  }
  __syncthreads();
  for (int e = t; e < 4096; e += 1024) {
    const int r = e >> 6, c = e & 63;
    float x = tri_get(curF, r, c);
    u16 hh, ll; split2(x, hh, ll); pgh[e] = hh; pgl[e] = ll;
    const float a1v = tri_get(tri1, r, c);
    wsA1[e] = a1v;
    split2(a1v, hh, ll); a1h[e] = hh; a1l[e] = ll;
  }
  if (t < 64) {
    float acc = 0.f;
    for (int m = 0; m < 64; ++m) acc += Cg[m] * tri_get(tri0, t, m);
    Kl[t] = acc;
  }
  __syncthreads();
  u16* wh = (u16*)(ws + WS_WH);
  u16* wl = (u16*)(ws + WS_WL);
  for (int e = t; e < 8192; e += 1024) {
    const int i = e >> 6, j = e & 63;
    float wv;
    if (i < 64) wv = ((i >= j) ? Kl[i - j] : 0.f) + ((i == j) ? D0 : 0.f);
    else        wv = tri_get(tri0, 63 - j, i - 64);   // gB[m][jj] = gBT[jj][m]
    u16 hh, ll; split2(wv, hh, ll);
    wh[e] = hh;
    wl[e] = ll;
  }
}

// -------- fused scan, NGRP=32 superchunks of GLEN=4 chunks -------------------
// Wave = rowgroup R (16 rows) x superchunk g. 4096 waves per kernel (4/SIMD).
// The SL relayout is wave-private: DS ops from one wave complete in order, so
// NO __syncthreads is needed around it (removing it decouples the 4 waves).

// E-kernel: read u, local scan from s=0 -> E_g.
__global__ void __launch_bounds__(256, 2)
ssm_scan_e(float* __restrict__ ws, const float* __restrict__ u) {
  __shared__ float SL[4][16 * 68];
  const int lane = threadIdx.x & 63;
  const int n = lane & 15, q = lane >> 4;
  const int wid = blockIdx.x * 4 + (threadIdx.x >> 6);
  const int R = (wid >> 5) * 16;
  const int g = wid & 31;
  float* sl = SL[threadIdx.x >> 6];

  const u16* ph = (const u16*)(ws + WS_PH);
  const u16* pl = (const u16*)(ws + WS_PL);
  const u16* wh = (const u16*)(ws + WS_WH);
  const u16* wl = (const u16*)(ws + WS_WL);
  bf16x8 Ph[4][2], Pl[4][2], Wbh[4][2], Wbl[4][2];
#pragma unroll
  for (int mt = 0; mt < 4; ++mt)
#pragma unroll
    for (int ks = 0; ks < 2; ++ks) {
      const int off  = (mt * 16 + n) * 64 + ks * 32 + q * 8;
      const int offb = off + 64 * 64;             // Wbot rows 64..127
      Ph[mt][ks]  = *(const bf16x8*)(ph + off);
      Pl[mt][ks]  = *(const bf16x8*)(pl + off);
      Wbh[mt][ks] = *(const bf16x8*)(wh + offb);
      Wbl[mt][ks] = *(const bf16x8*)(wl + offb);
    }

  bf16x8 Sbh[2], Sbl[2];
#pragma unroll
  for (int ks = 0; ks < 2; ++ks)
#pragma unroll
    for (int j = 0; j < 8; ++j) { Sbh[ks][j] = 0; Sbl[ks][j] = 0; }

  const int cb = g * GLEN;
  const float* ub = u + (size_t)(R + n) * LSEQ + cb * 64 + q * 8;

  f32x4 f0 = *(const f32x4*)(ub);
  f32x4 f1 = *(const f32x4*)(ub + 4);
  f32x4 f2 = *(const f32x4*)(ub + 32);
  f32x4 f3 = *(const f32x4*)(ub + 36);

  for (int c8 = 0; c8 < GLEN; ++c8) {
    bf16x8 ubh[2], ubl[2];
    {
      float xs0[8] = {f0[0], f0[1], f0[2], f0[3], f1[0], f1[1], f1[2], f1[3]};
      float xs1[8] = {f2[0], f2[1], f2[2], f2[3], f3[0], f3[1], f3[2], f3[3]};
#pragma unroll
      for (int j = 0; j < 8; ++j) {
        u16 hh, ll;
        split2(xs0[j], hh, ll); ubh[0][j] = (short)hh; ubl[0][j] = (short)ll;
        split2(xs1[j], hh, ll); ubh[1][j] = (short)hh; ubl[1][j] = (short)ll;
      }
    }
    const int cn = (c8 + 1 < GLEN) ? (c8 + 1) : c8;
    const float* nb = ub + cn * 64;
    f0 = *(const f32x4*)(nb);
    f1 = *(const f32x4*)(nb + 4);
    f2 = *(const f32x4*)(nb + 32);
    f3 = *(const f32x4*)(nb + 36);

    f32x4 accS[4];
#pragma unroll
    for (int mt = 0; mt < 4; ++mt) {
      f32x4 as = {0.f, 0.f, 0.f, 0.f};
#define MF(a, b) as = __builtin_amdgcn_mfma_f32_16x16x32_bf16(a, b, as, 0, 0, 0)
      MF(Wbh[mt][0], ubh[0]); MF(Wbh[mt][1], ubh[1]);      // v = Wbot@u
      MF(Wbh[mt][0], ubl[0]); MF(Wbh[mt][1], ubl[1]);
      MF(Wbl[mt][0], ubh[0]); MF(Wbl[mt][1], ubh[1]);
      MF(Ph[mt][0], Sbh[0]);  MF(Ph[mt][1], Sbh[1]);       // + P@S
      MF(Ph[mt][0], Sbl[0]);  MF(Ph[mt][1], Sbl[1]);
      MF(Pl[mt][0], Sbh[0]);  MF(Pl[mt][1], Sbh[1]);
#undef MF
      accS[mt] = as;
    }

    if (c8 + 1 < GLEN) {
      // wave-private relayout: no barrier (in-wave DS ordering suffices)
#pragma unroll
      for (int mt = 0; mt < 4; ++mt)
        *(f32x4*)(&sl[n * 68 + mt * 16 + q * 4]) = accS[mt];
#pragma unroll
      for (int ks = 0; ks < 2; ++ks) {
        f32x4 s0 = *(const f32x4*)(&sl[n * 68 + ks * 32 + q * 8]);
        f32x4 s1 = *(const f32x4*)(&sl[n * 68 + ks * 32 + q * 8 + 4]);
#pragma unroll
        for (int j = 0; j < 4; ++j) {
          u16 hh, ll;
          split2(s0[j], hh, ll); Sbh[ks][j] = (short)hh; Sbl[ks][j] = (short)ll;
          split2(s1[j], hh, ll); Sbh[ks][j + 4] = (short)hh; Sbl[ks][j + 4] = (short)ll;
        }
      }
    } else {
      float* eb = ws + WS_E + ((size_t)(R + n) * NGRP + g) * 64 + q * 4;
#pragma unroll
      for (int mt = 0; mt < 4; ++mt)
        *(f32x4*)(eb + mt * 16) = accS[mt];
    }
  }
}

// sigma-kernel: per row-group boundary scan sg_{g+1} = P^GLEN@sg_g + E_g.
__global__ void __launch_bounds__(256, 2)
ssm_scan_sg(float* __restrict__ ws) {
  __shared__ float SL[4][16 * 68];
  const int lane = threadIdx.x & 63;
  const int n = lane & 15, q = lane >> 4;
  const int wid = blockIdx.x * 4 + (threadIdx.x >> 6);
  const int R = wid * 16;
  float* sl = SL[threadIdx.x >> 6];

  const u16* pgh = (const u16*)(ws + WS_PGH);
  const u16* pgl = (const u16*)(ws + WS_PGL);
  bf16x8 Ph[4][2], Pl[4][2];
#pragma unroll
  for (int mt = 0; mt < 4; ++mt)
#pragma unroll
    for (int ks = 0; ks < 2; ++ks) {
      int off = (mt * 16 + n) * 64 + ks * 32 + q * 8;
      Ph[mt][ks] = *(const bf16x8*)(pgh + off);
      Pl[mt][ks] = *(const bf16x8*)(pgl + off);
    }

  bf16x8 Sbh[2], Sbl[2];
#pragma unroll
  for (int ks = 0; ks < 2; ++ks)
#pragma unroll
    for (int j = 0; j < 8; ++j) { Sbh[ks][j] = 0; Sbl[ks][j] = 0; }

  const float* erow = ws + WS_E + ((size_t)(R + n) * NGRP) * 64 + q * 4;
  float*       srow = ws + WS_SG + ((size_t)(R + n) * NGRP) * 64 + q * 4;

  {
    f32x4 z = {0.f, 0.f, 0.f, 0.f};
#pragma unroll
    for (int mt = 0; mt < 4; ++mt) *(f32x4*)(srow + mt * 16) = z;
  }

  f32x4 ec[4];
#pragma unroll
  for (int mt = 0; mt < 4; ++mt) ec[mt] = *(const f32x4*)(erow + mt * 16);

  for (int g = 0; g < NGRP - 1; ++g) {
    const int gn = (g + 1 < NGRP - 1) ? (g + 1) : g;
    f32x4 en[4];
#pragma unroll
    for (int mt = 0; mt < 4; ++mt)
      en[mt] = *(const f32x4*)(erow + (size_t)gn * 64 + mt * 16);

    f32x4 accS[4];
#pragma unroll
    for (int mt = 0; mt < 4; ++mt) {
      f32x4 as = ec[mt];
#define MF(a, b) as = __builtin_amdgcn_mfma_f32_16x16x32_bf16(a, b, as, 0, 0, 0)
      MF(Ph[mt][0], Sbh[0]); MF(Ph[mt][1], Sbh[1]);
      MF(Ph[mt][0], Sbl[0]); MF(Ph[mt][1], Sbl[1]);
      MF(Pl[mt][0], Sbh[0]); MF(Pl[mt][1], Sbh[1]);
#undef MF
      accS[mt] = as;
    }

#pragma unroll
    for (int mt = 0; mt < 4; ++mt)
      *(f32x4*)(srow + (size_t)(g + 1) * 64 + mt * 16) = accS[mt];

    if (g + 1 < NGRP - 1) {
      // wave-private relayout: no barrier
#pragma unroll
      for (int mt = 0; mt < 4; ++mt)
        *(f32x4*)(&sl[n * 68 + mt * 16 + q * 4]) = accS[mt];
#pragma unroll
      for (int ks = 0; ks < 2; ++ks) {
        f32x4 s0 = *(const f32x4*)(&sl[n * 68 + ks * 32 + q * 8]);
        f32x4 s1 = *(const f32x4*)(&sl[n * 68 + ks * 32 + q * 8 + 4]);
#pragma unroll
        for (int j = 0; j < 4; ++j) {
          u16 hh, ll;
          split2(s0[j], hh, ll); Sbh[ks][j] = (short)hh; Sbl[ks][j] = (short)ll;
          split2(s1[j], hh, ll); Sbh[ks][j + 4] = (short)hh; Sbl[ks][j + 4] = (short)ll;
        }
      }
    }

    ec[0] = en[0]; ec[1] = en[1]; ec[2] = en[2]; ec[3] = en[3];
  }
}

// Main fused kernel: read u + SG, compute y = Wtop@u + A1@S_old, recurrence
// S' = P@S + Wbot@u. P + Wbot in VGPR; Wtop + A1 staged swizzled in LDS.
__global__ void __launch_bounds__(256, 2)
ssm_scan_main(const float* __restrict__ ws, const float* __restrict__ u,
              float* __restrict__ y) {
  __shared__ float SL[4][16 * 68];
  __shared__ __attribute__((aligned(16))) u16 WT[2][4096];   // Wtop hi/lo, swizzled
  __shared__ __attribute__((aligned(16))) u16 A1S[2][4096];  // A1  hi/lo, swizzled
  const int lane = threadIdx.x & 63;
  const int n = lane & 15, q = lane >> 4;
  const int wid = blockIdx.x * 4 + (threadIdx.x >> 6);
  const int R = (wid >> 5) * 16;
  const int g = wid & 31;
  float* sl = SL[threadIdx.x >> 6];

  // stage Wtop + A1 into LDS (swizzled)
  {
    const u16* whg  = (const u16*)(ws + WS_WH);
    const u16* wlg  = (const u16*)(ws + WS_WL);
    const u16* a1hg = (const u16*)(ws + WS_A1H);
    const u16* a1lg = (const u16*)(ws + WS_A1L);
    for (int e = threadIdx.x; e < 4096; e += 256) {
      const int s = swz(e >> 6, e & 63);
      WT[0][s]  = whg[e];  WT[1][s]  = wlg[e];
      A1S[0][s] = a1hg[e]; A1S[1][s] = a1lg[e];
    }
  }

  const u16* ph = (const u16*)(ws + WS_PH);
  const u16* pl = (const u16*)(ws + WS_PL);
  const u16* wh = (const u16*)(ws + WS_WH);
  const u16* wl = (const u16*)(ws + WS_WL);
  bf16x8 Ph[4][2], Pl[4][2], Wbh[4][2], Wbl[4][2];
#pragma unroll
  for (int mt = 0; mt < 4; ++mt)
#pragma unroll
    for (int ks = 0; ks < 2; ++ks) {
      const int off  = (mt * 16 + n) * 64 + ks * 32 + q * 8;
      const int offb = off + 64 * 64;
      Ph[mt][ks]  = *(const bf16x8*)(ph + off);
      Pl[mt][ks]  = *(const bf16x8*)(pl + off);
      Wbh[mt][ks] = *(const bf16x8*)(wh + offb);
      Wbl[mt][ks] = *(const bf16x8*)(wl + offb);
    }

  // S init from sg_g
  bf16x8 Sbh[2], Sbl[2];
  {
    const float* sgp = ws + WS_SG + ((size_t)(R + n) * NGRP + g) * 64;
#pragma unroll
    for (int ks = 0; ks < 2; ++ks) {
      f32x4 s0 = *(const f32x4*)(sgp + ks * 32 + q * 8);
      f32x4 s1 = *(const f32x4*)(sgp + ks * 32 + q * 8 + 4);
#pragma unroll
      for (int j = 0; j < 4; ++j) {
        u16 hh, ll;
        split2(s0[j], hh, ll); Sbh[ks][j] = (short)hh; Sbl[ks][j] = (short)ll;
        split2(s1[j], hh, ll); Sbh[ks][j + 4] = (short)hh; Sbl[ks][j + 4] = (short)ll;
      }
    }
  }

  const int cb = g * GLEN;
  const float* ub = u + (size_t)(R + n) * LSEQ + cb * 64 + q * 8;
  float*     yrow = y + (size_t)(R + n) * LSEQ + q * 4;

  f32x4 f0 = *(const f32x4*)(ub);
  f32x4 f1 = *(const f32x4*)(ub + 4);
  f32x4 f2 = *(const f32x4*)(ub + 32);
  f32x4 f3 = *(const f32x4*)(ub + 36);

  __syncthreads();   // staging visible (the one real cross-wave barrier)

  for (int c8 = 0; c8 < GLEN; ++c8) {
    const int c = cb + c8;
    bf16x8 ubh[2], ubl[2];
    {
      float xs0[8] = {f0[0], f0[1], f0[2], f0[3], f1[0], f1[1], f1[2], f1[3]};
      float xs1[8] = {f2[0], f2[1], f2[2], f2[3], f3[0], f3[1], f3[2], f3[3]};
#pragma unroll
      for (int j = 0; j < 8; ++j) {
        u16 hh, ll;
        split2(xs0[j], hh, ll); ubh[0][j] = (short)hh; ubl[0][j] = (short)ll;
        split2(xs1[j], hh, ll); ubh[1][j] = (short)hh; ubl[1][j] = (short)ll;
      }
    }
    const int cn = (c8 + 1 < GLEN) ? (c8 + 1) : c8;
    const float* nb = ub + cn * 64;
    f0 = *(const f32x4*)(nb);
    f1 = *(const f32x4*)(nb + 4);
    f2 = *(const f32x4*)(nb + 32);
    f3 = *(const f32x4*)(nb + 36);

    // accY = Wtop@u + A1@S_old   (frags streamed from LDS)
#pragma unroll
    for (int mt = 0; mt < 4; ++mt) {
      f32x4 ay = {0.f, 0.f, 0.f, 0.f};
      const int o0 = swz(mt * 16 + n, q * 8);
      const int o1 = swz(mt * 16 + n, 32 + q * 8);
      bf16x8 th0 = *(const bf16x8*)(&WT[0][o0]);
      bf16x8 th1 = *(const bf16x8*)(&WT[0][o1]);
      bf16x8 tl0 = *(const bf16x8*)(&WT[1][o0]);
      bf16x8 tl1 = *(const bf16x8*)(&WT[1][o1]);
#define MF(a, b) ay = __builtin_amdgcn_mfma_f32_16x16x32_bf16(a, b, ay, 0, 0, 0)
      MF(th0, ubh[0]); MF(th1, ubh[1]);
      MF(th0, ubl[0]); MF(th1, ubl[1]);
      MF(tl0, ubh[0]); MF(tl1, ubh[1]);
      bf16x8 ah0 = *(const bf16x8*)(&A1S[0][o0]);
      bf16x8 ah1 = *(const bf16x8*)(&A1S[0][o1]);
      bf16x8 al0 = *(const bf16x8*)(&A1S[1][o0]);
      bf16x8 al1 = *(const bf16x8*)(&A1S[1][o1]);
      MF(ah0, Sbh[0]); MF(ah1, Sbh[1]);
      MF(ah0, Sbl[0]); MF(ah1, Sbl[1]);
      MF(al0, Sbh[0]); MF(al1, Sbh[1]);
#undef MF
      *(f32x4*)(yrow + (size_t)c * 64 + mt * 16) = ay;
    }

    // S' = P@S + v  (skip on superchunk-final chunk: S' unused)
    if (c8 + 1 < GLEN) {
      f32x4 accS[4];
#pragma unroll
      for (int mt = 0; mt < 4; ++mt) {
        f32x4 as = {0.f, 0.f, 0.f, 0.f};
#define MF(a, b) as = __builtin_amdgcn_mfma_f32_16x16x32_bf16(a, b, as, 0, 0, 0)
        MF(Wbh[mt][0], ubh[0]); MF(Wbh[mt][1], ubh[1]);    // v  (identical order
        MF(Wbh[mt][0], ubl[0]); MF(Wbh[mt][1], ubl[1]);    //    to ssm_scan_e)
        MF(Wbl[mt][0], ubh[0]); MF(Wbl[mt][1], ubh[1]);
        MF(Ph[mt][0], Sbh[0]);  MF(Ph[mt][1], Sbh[1]);
        MF(Ph[mt][0], Sbl[0]);  MF(Ph[mt][1], Sbl[1]);
        MF(Pl[mt][0], Sbh[0]);  MF(Pl[mt][1], Sbh[1]);
#undef MF
        accS[mt] = as;
      }
      // wave-private relayout: no barrier
#pragma unroll
      for (int mt = 0; mt < 4; ++mt)
        *(f32x4*)(&sl[n * 68 + mt * 16 + q * 4]) = accS[mt];
#pragma unroll
      for (int ks = 0; ks < 2; ++ks) {
        f32x4 s0 = *(const f32x4*)(&sl[n * 68 + ks * 32 + q * 8]);
        f32x4 s1 = *(const f32x4*)(&sl[n * 68 + ks * 32 + q * 8 + 4]);
#pragma unroll
        for (int j = 0; j < 4; ++j) {
          u16 hh, ll;
          split2(s0[j], hh, ll); Sbh[ks][j] = (short)hh; Sbl[ks][j] = (short)ll;
          split2(s1[j], hh, ll); Sbh[ks][j + 4] = (short)hh; Sbl[ks][j + 4] = (short)ll;
        }
      }
    }
  }
}

extern "C" void kernel_launch(void* const* d_in, const int* in_sizes, int n_in,
                              void* d_out, int out_size, void* d_ws, size_t ws_size,
                              hipStream_t stream) {
  const float* u  = (const float*)d_in[0];
  const float* A  = (const float*)d_in[1];
  const float* B  = (const float*)d_in[2];
  const float* C  = (const float*)d_in[3];
  const float* D  = (const float*)d_in[4];
  const float* ls = (const float*)d_in[5];
  float* ws  = (float*)d_ws;
  float* out = (float*)d_out;

  ssm_pre<<<dim3(1), dim3(1024), 0, stream>>>(A, B, C, D, ls, ws);
  ssm_scan_e<<<dim3(1024), dim3(256), 0, stream>>>(ws, u);
  ssm_scan_sg<<<dim3(32), dim3(256), 0, stream>>>(ws);
  ssm_scan_main<<<dim3(1024), dim3(256), 0, stream>>>(ws, u, out);
}

// Round 7
// 250.795 us; speedup vs baseline: 1.2074x; 1.2074x over previous
//
#include <hip/hip_runtime.h>
#include <math.h>

#define LSEQ   8192
#define CHUNK  64
#define NCHUNK 128
#define NBATCH 2048
#define NGRP   32      /* superchunks */
#define GLEN   4       /* chunks per superchunk: NGRP*GLEN == NCHUNK */

// ws float layout: E and SG live in the dead v-slot [0, T0); tables at T0+.
#define WS_E   0                            /* NBATCH*NGRP*64 = 4194304 floats */
#define WS_SG  (NBATCH * NGRP * 64)         /* same size; both fit in old v slot */
#define T0     (NBATCH * NCHUNK * 64)
#define WS_P   (T0)
#define WS_A1  (T0 + 4096)
#define WS_K   (T0 + 8192)
#define WS_WH  (T0 + 8256)    /* 4096 floats = 8192 bf16: W hi, row-major 128x64 */
#define WS_WL  (T0 + 12352)   /* 4096 floats: W lo */
#define WS_PH  (T0 + 16448)   /* 2048 floats = 4096 bf16: P hi, row-major 64x64 */
#define WS_PL  (T0 + 18496)
#define WS_A1H (T0 + 20544)
#define WS_A1L (T0 + 22592)
#define WS_PGH (T0 + 24640)   /* P^GLEN hi (boundary matrix for sg) */
#define WS_PGL (T0 + 26688)

typedef short bf16x8 __attribute__((ext_vector_type(8)));
typedef float f32x4  __attribute__((ext_vector_type(4)));
typedef unsigned short u16;

__device__ __forceinline__ u16 bf16rne(float x) {
  unsigned b = __builtin_bit_cast(unsigned, x);
  return (u16)((b + 0x7fffu + ((b >> 16) & 1u)) >> 16);
}
__device__ __forceinline__ float bf2f(u16 h) {
  return __builtin_bit_cast(float, ((unsigned)h) << 16);
}
__device__ __forceinline__ void split2(float x, u16& h, u16& l) {
  h = bf16rne(x);
  l = bf16rne(x - bf2f(h));
}
__device__ __forceinline__ void split3(float x, u16& h, u16& m, u16& l) {
  h = bf16rne(x);
  float r = x - bf2f(h);
  m = bf16rne(r);
  r -= bf2f(m);
  l = bf16rne(r);
}

// XOR swizzle on 8-col groups: kills the stride-128B same-bank pattern for
// ds_read_b128 fragment reads (G4/T2).
__device__ __forceinline__ int swz(int r, int c) {
  return r * 64 + (c ^ ((r & 7) << 3));
}
__device__ __forceinline__ float tri_get(const u16* p, int r, int c) {
  const int e = swz(r, c);
  return bf2f(p[e]) + bf2f(p[4096 + e]) + bf2f(p[8192 + e]);
}

// ---------------- pre: MFMA triple-bf16 64x64 matmuls (round-4, verified) ----
__device__ __forceinline__ void mfma_tile3(
    const u16* __restrict__ A3, const u16* __restrict__ B3, u16* __restrict__ D3,
    int mt, int nt, int aShift,
    const u16* add1, const u16* add2, int addI, int rLo, int rHi) {
  const int lane = threadIdx.x & 63;
  const int n = lane & 15, q = lane >> 4;
  int ar = mt * 16 + n - aShift;
  ar = ar < 0 ? 0 : (ar > 63 ? 63 : ar);
  const int bc = nt * 16 + n;
  bf16x8 ah[2], am[2], al[2], bh[2], bm[2], bl[2];
#pragma unroll
  for (int ks = 0; ks < 2; ++ks) {
    const int ao = swz(ar, ks * 32 + q * 8);
    const int bo = swz(bc, ks * 32 + q * 8);
    ah[ks] = *(const bf16x8*)(A3 + ao);
    am[ks] = *(const bf16x8*)(A3 + 4096 + ao);
    al[ks] = *(const bf16x8*)(A3 + 8192 + ao);
    bh[ks] = *(const bf16x8*)(B3 + bo);
    bm[ks] = *(const bf16x8*)(B3 + 4096 + bo);
    bl[ks] = *(const bf16x8*)(B3 + 8192 + bo);
  }
  f32x4 acc = {0.f, 0.f, 0.f, 0.f};
#define MF(a, b) acc = __builtin_amdgcn_mfma_f32_16x16x32_bf16(a, b, acc, 0, 0, 0)
  MF(ah[0], bh[0]); MF(ah[1], bh[1]);
  MF(ah[0], bm[0]); MF(ah[1], bm[1]);
  MF(am[0], bh[0]); MF(am[1], bh[1]);
  MF(ah[0], bl[0]); MF(ah[1], bl[1]);
  MF(am[0], bm[0]); MF(am[1], bm[1]);
  MF(al[0], bh[0]); MF(al[1], bh[1]);
#undef MF
#pragma unroll
  for (int j = 0; j < 4; ++j) {
    const int i = mt * 16 + q * 4 + j, c = nt * 16 + n;
    float v = acc[j];
    if (add1) v += tri_get(add1, i, c);
    if (add2) v += tri_get(add2, i, c);
    if (addI && i == c) v += 1.f;
    if (i >= rLo && i < rHi) {
      u16 h3, m3, l3; split3(v, h3, m3, l3);
      const int e = swz(i, c);
      D3[e] = h3; D3[4096 + e] = m3; D3[8192 + e] = l3;
    }
  }
}

__device__ __forceinline__ void pair_phase(
    const u16* Pf, const u16* Qt, u16* Fn, u16* Tn,
    const u16* addF1, const u16* addT1, int addI) {
  __syncthreads();
  const int w = threadIdx.x >> 6;
#pragma unroll
  for (int tix = w; tix < 32; tix += 16) {
    if (tix < 16) mfma_tile3(Pf, Qt, Fn, tix >> 2, tix & 3, 0, addF1, 0, addI, 0, 64);
    else { const int s = tix - 16; mfma_tile3(Qt, Pf, Tn, s >> 2, s & 3, 0, addT1, 0, addI, 0, 64); }
  }
}
__device__ __forceinline__ void single_phase(
    const u16* A3, const u16* B3, u16* D3,
    const u16* add1, const u16* add2, int addI) {
  __syncthreads();
  const int w = threadIdx.x >> 6;
  mfma_tile3(A3, B3, D3, w >> 2, w & 3, 0, add1, add2, addI, 0, 64);
}

__global__ void __launch_bounds__(1024)
ssm_pre(const float* __restrict__ Ag, const float* __restrict__ Bg,
        const float* __restrict__ Cg, const float* __restrict__ Dg,
        const float* __restrict__ lsg, float* __restrict__ ws) {
  __shared__ __attribute__((aligned(16))) u16 TRI[6][3 * 4096];
  __shared__ float Kl[64];
  u16* tri0 = TRI[0]; u16* tri1 = TRI[1]; u16* tri2 = TRI[2];
  u16* tri3 = TRI[3]; u16* tri4 = TRI[4]; u16* tri5 = TRI[5];

  const int t = threadIdx.x;
  const int w = t >> 6;
  const float step = expf(lsg[0]);
  const float hstep = 0.5f * step;
  const float D0 = Dg[0];

  float* Xf = (float*)tri2;
  for (int e = t; e < 4096; e += 1024) {
    const float x = hstep * Ag[e];
    Xf[e] = x;
    u16 h3, m3, l3; split3(x, h3, m3, l3);
    const int s = swz(e >> 6, e & 63);
    tri0[s] = h3; tri0[4096 + s] = m3; tri0[8192 + s] = l3;
  }
  __syncthreads();
  for (int e = t; e < 4096; e += 1024) {
    const int r = e >> 6, c = e & 63;
    const float x = Xf[c * 64 + r];
    u16 h3, m3, l3; split3(x, h3, m3, l3);
    const int s = swz(r, c);
    tri1[s] = h3; tri1[4096 + s] = m3; tri1[8192 + s] = l3;
  }
  pair_phase(tri0, tri1, tri2, tri3, 0, 0, 0);          // X2
  pair_phase(tri2, tri3, tri4, tri5, 0, 0, 0);          // X4
  single_phase(tri4, tri3, tri0, tri4, tri2, 1);        // T1
  single_phase(tri3, tri4, tri2, tri3, tri5, 1);        // T1T
  pair_phase(tri0, tri1, tri3, tri5, tri0, tri2, 0);    // BL / BLT
  pair_phase(tri3, tri1, tri4, tri2, tri3, tri5, 0);    // Ab / AbT

  __syncthreads();
  if (t < 64) {
    float acc = 0.f;
    for (int m = 0; m < 64; ++m) acc += tri_get(tri3, t, m) * Bg[m];  // BL row t
    const float bb = step * acc;
    u16 h3, m3, l3; split3(bb, h3, m3, l3);
    const int s = swz(0, t);
    tri0[s] = h3; tri0[4096 + s] = m3; tri0[8192 + s] = l3;
  } else if (t < 128) {
    const int r = t - 64;
    float acc = 0.f;
    for (int m = 0; m < 64; ++m) acc += tri_get(tri2, r, m) * Cg[m];  // AbT row r
    u16 h3, m3, l3; split3(acc, h3, m3, l3);
    const int s = swz(0, r);
    tri1[s] = h3; tri1[4096 + s] = m3; tri1[8192 + s] = l3;
  }

  u16 *curF = tri4, *curT = tri2, *nxtF = tri3, *nxtT = tri5;
  for (int k = 1; k <= 32; k <<= 1) {
    __syncthreads();
    const int mtLo = k >> 4, mtHi = (2 * k - 1) >> 4;
    const int cnt = (mtHi - mtLo + 1) * 4;
    const int total = 32 + 2 * cnt;
    for (int tix = w; tix < total; tix += 16) {
      if (tix < 16) {
        mfma_tile3(curF, curT, nxtF, tix >> 2, tix & 3, 0, 0, 0, 0, 0, 64);
      } else if (tix < 32) {
        const int s = tix - 16;
        mfma_tile3(curT, curF, nxtT, s >> 2, s & 3, 0, 0, 0, 0, 0, 64);
      } else if (tix < 32 + cnt) {
        const int s = tix - 32;
        mfma_tile3(tri0, curF, tri0, mtLo + (s >> 2), s & 3, k, 0, 0, 0, k, 2 * k);
      } else {
        const int s = tix - 32 - cnt;
        mfma_tile3(tri1, curT, tri1, mtLo + (s >> 2), s & 3, k, 0, 0, 0, k, 2 * k);
      }
    }
    u16* tmp;
    tmp = curF; curF = nxtF; nxtF = tmp;
    tmp = curT; curT = nxtT; nxtT = tmp;
  }

  __syncthreads();
  float* wsP  = ws + WS_P;
  float* wsA1 = ws + WS_A1;
  u16* ph  = (u16*)(ws + WS_PH);
  u16* pl  = (u16*)(ws + WS_PL);
  u16* a1h = (u16*)(ws + WS_A1H);
  u16* a1l = (u16*)(ws + WS_A1L);
  u16* pgh = (u16*)(ws + WS_PGH);
  u16* pgl = (u16*)(ws + WS_PGL);
  for (int e = t; e < 4096; e += 1024) {
    const float x = tri_get(curF, e >> 6, e & 63);
    wsP[e] = x;
    u16 hh, ll; split2(x, hh, ll); ph[e] = hh; pl[e] = ll;
  }
  // tail: P^2, P^4 = P^GLEN (GLEN==4) — two pair squarings
  for (int r2 = 0; r2 < 2; ++r2) {
    pair_phase(curF, curT, nxtF, nxtT, 0, 0, 0);
    u16* tmp;
    tmp = curF; curF = nxtF; nxtF = tmp;
    tmp = curT; curT = nxtT; nxtT = tmp;
  }
  __syncthreads();
  for (int e = t; e < 4096; e += 1024) {
    const int r = e >> 6, c = e & 63;
    float x = tri_get(curF, r, c);
    u16 hh, ll; split2(x, hh, ll); pgh[e] = hh; pgl[e] = ll;
    const float a1v = tri_get(tri1, r, c);
    wsA1[e] = a1v;
    split2(a1v, hh, ll); a1h[e] = hh; a1l[e] = ll;
  }
  if (t < 64) {
    float acc = 0.f;
    for (int m = 0; m < 64; ++m) acc += Cg[m] * tri_get(tri0, t, m);
    Kl[t] = acc;
  }
  __syncthreads();
  u16* wh = (u16*)(ws + WS_WH);
  u16* wl = (u16*)(ws + WS_WL);
  for (int e = t; e < 8192; e += 1024) {
    const int i = e >> 6, j = e & 63;
    float wv;
    if (i < 64) wv = ((i >= j) ? Kl[i - j] : 0.f) + ((i == j) ? D0 : 0.f);
    else        wv = tri_get(tri0, 63 - j, i - 64);   // gB[m][jj] = gBT[jj][m]
    u16 hh, ll; split2(wv, hh, ll);
    wh[e] = hh;
    wl[e] = ll;
  }
}

// -------- fused scan, NGRP=32 superchunks of GLEN=4 chunks -------------------
// Wave = rowgroup R (16 rows) x superchunk g. 4096 waves per kernel (4/SIMD).
// NOTE (round-6 post-mortem): the SL relayout IS wave-private, but removing
// the barriers let the compiler software-pipeline across chunk iterations,
// doubling live state -> ~110 MB scratch-spill round-trip and a 2.5x
// regression. The barriers are kept as cheap scheduling fences.

// E-kernel: read u, local scan from s=0 -> E_g.
__global__ void __launch_bounds__(256, 2)
ssm_scan_e(float* __restrict__ ws, const float* __restrict__ u) {
  __shared__ float SL[4][16 * 68];
  const int lane = threadIdx.x & 63;
  const int n = lane & 15, q = lane >> 4;
  const int wid = blockIdx.x * 4 + (threadIdx.x >> 6);
  const int R = (wid >> 5) * 16;
  const int g = wid & 31;
  float* sl = SL[threadIdx.x >> 6];

  const u16* ph = (const u16*)(ws + WS_PH);
  const u16* pl = (const u16*)(ws + WS_PL);
  const u16* wh = (const u16*)(ws + WS_WH);
  const u16* wl = (const u16*)(ws + WS_WL);
  bf16x8 Ph[4][2], Pl[4][2], Wbh[4][2], Wbl[4][2];
#pragma unroll
  for (int mt = 0; mt < 4; ++mt)
#pragma unroll
    for (int ks = 0; ks < 2; ++ks) {
      const int off  = (mt * 16 + n) * 64 + ks * 32 + q * 8;
      const int offb = off + 64 * 64;             // Wbot rows 64..127
      Ph[mt][ks]  = *(const bf16x8*)(ph + off);
      Pl[mt][ks]  = *(const bf16x8*)(pl + off);
      Wbh[mt][ks] = *(const bf16x8*)(wh + offb);
      Wbl[mt][ks] = *(const bf16x8*)(wl + offb);
    }

  bf16x8 Sbh[2], Sbl[2];
#pragma unroll
  for (int ks = 0; ks < 2; ++ks)
#pragma unroll
    for (int j = 0; j < 8; ++j) { Sbh[ks][j] = 0; Sbl[ks][j] = 0; }

  const int cb = g * GLEN;
  const float* ub = u + (size_t)(R + n) * LSEQ + cb * 64 + q * 8;

  f32x4 f0 = *(const f32x4*)(ub);
  f32x4 f1 = *(const f32x4*)(ub + 4);
  f32x4 f2 = *(const f32x4*)(ub + 32);
  f32x4 f3 = *(const f32x4*)(ub + 36);

  for (int c8 = 0; c8 < GLEN; ++c8) {
    bf16x8 ubh[2], ubl[2];
    {
      float xs0[8] = {f0[0], f0[1], f0[2], f0[3], f1[0], f1[1], f1[2], f1[3]};
      float xs1[8] = {f2[0], f2[1], f2[2], f2[3], f3[0], f3[1], f3[2], f3[3]};
#pragma unroll
      for (int j = 0; j < 8; ++j) {
        u16 hh, ll;
        split2(xs0[j], hh, ll); ubh[0][j] = (short)hh; ubl[0][j] = (short)ll;
        split2(xs1[j], hh, ll); ubh[1][j] = (short)hh; ubl[1][j] = (short)ll;
      }
    }
    const int cn = (c8 + 1 < GLEN) ? (c8 + 1) : c8;
    const float* nb = ub + cn * 64;
    f0 = *(const f32x4*)(nb);
    f1 = *(const f32x4*)(nb + 4);
    f2 = *(const f32x4*)(nb + 32);
    f3 = *(const f32x4*)(nb + 36);

    f32x4 accS[4];
#pragma unroll
    for (int mt = 0; mt < 4; ++mt) {
      f32x4 as = {0.f, 0.f, 0.f, 0.f};
#define MF(a, b) as = __builtin_amdgcn_mfma_f32_16x16x32_bf16(a, b, as, 0, 0, 0)
      MF(Wbh[mt][0], ubh[0]); MF(Wbh[mt][1], ubh[1]);      // v = Wbot@u
      MF(Wbh[mt][0], ubl[0]); MF(Wbh[mt][1], ubl[1]);
      MF(Wbl[mt][0], ubh[0]); MF(Wbl[mt][1], ubh[1]);
      MF(Ph[mt][0], Sbh[0]);  MF(Ph[mt][1], Sbh[1]);       // + P@S
      MF(Ph[mt][0], Sbl[0]);  MF(Ph[mt][1], Sbl[1]);
      MF(Pl[mt][0], Sbh[0]);  MF(Pl[mt][1], Sbh[1]);
#undef MF
      accS[mt] = as;
    }

    if (c8 + 1 < GLEN) {
      __syncthreads();   // scheduling fence (see note above)
#pragma unroll
      for (int mt = 0; mt < 4; ++mt)
        *(f32x4*)(&sl[n * 68 + mt * 16 + q * 4]) = accS[mt];
      __syncthreads();
#pragma unroll
      for (int ks = 0; ks < 2; ++ks) {
        f32x4 s0 = *(const f32x4*)(&sl[n * 68 + ks * 32 + q * 8]);
        f32x4 s1 = *(const f32x4*)(&sl[n * 68 + ks * 32 + q * 8 + 4]);
#pragma unroll
        for (int j = 0; j < 4; ++j) {
          u16 hh, ll;
          split2(s0[j], hh, ll); Sbh[ks][j] = (short)hh; Sbl[ks][j] = (short)ll;
          split2(s1[j], hh, ll); Sbh[ks][j + 4] = (short)hh; Sbl[ks][j + 4] = (short)ll;
        }
      }
    } else {
      float* eb = ws + WS_E + ((size_t)(R + n) * NGRP + g) * 64 + q * 4;
#pragma unroll
      for (int mt = 0; mt < 4; ++mt)
        *(f32x4*)(eb + mt * 16) = accS[mt];
    }
  }
}

// sigma-kernel: per row-group boundary scan sg_{g+1} = P^GLEN@sg_g + E_g.
__global__ void __launch_bounds__(256, 2)
ssm_scan_sg(float* __restrict__ ws) {
  __shared__ float SL[4][16 * 68];
  const int lane = threadIdx.x & 63;
  const int n = lane & 15, q = lane >> 4;
  const int wid = blockIdx.x * 4 + (threadIdx.x >> 6);
  const int R = wid * 16;
  float* sl = SL[threadIdx.x >> 6];

  const u16* pgh = (const u16*)(ws + WS_PGH);
  const u16* pgl = (const u16*)(ws + WS_PGL);
  bf16x8 Ph[4][2], Pl[4][2];
#pragma unroll
  for (int mt = 0; mt < 4; ++mt)
#pragma unroll
    for (int ks = 0; ks < 2; ++ks) {
      int off = (mt * 16 + n) * 64 + ks * 32 + q * 8;
      Ph[mt][ks] = *(const bf16x8*)(pgh + off);
      Pl[mt][ks] = *(const bf16x8*)(pgl + off);
    }

  bf16x8 Sbh[2], Sbl[2];
#pragma unroll
  for (int ks = 0; ks < 2; ++ks)
#pragma unroll
    for (int j = 0; j < 8; ++j) { Sbh[ks][j] = 0; Sbl[ks][j] = 0; }

  const float* erow = ws + WS_E + ((size_t)(R + n) * NGRP) * 64 + q * 4;
  float*       srow = ws + WS_SG + ((size_t)(R + n) * NGRP) * 64 + q * 4;

  {
    f32x4 z = {0.f, 0.f, 0.f, 0.f};
#pragma unroll
    for (int mt = 0; mt < 4; ++mt) *(f32x4*)(srow + mt * 16) = z;
  }

  f32x4 ec[4];
#pragma unroll
  for (int mt = 0; mt < 4; ++mt) ec[mt] = *(const f32x4*)(erow + mt * 16);

  for (int g = 0; g < NGRP - 1; ++g) {
    const int gn = (g + 1 < NGRP - 1) ? (g + 1) : g;
    f32x4 en[4];
#pragma unroll
    for (int mt = 0; mt < 4; ++mt)
      en[mt] = *(const f32x4*)(erow + (size_t)gn * 64 + mt * 16);

    f32x4 accS[4];
#pragma unroll
    for (int mt = 0; mt < 4; ++mt) {
      f32x4 as = ec[mt];
#define MF(a, b) as = __builtin_amdgcn_mfma_f32_16x16x32_bf16(a, b, as, 0, 0, 0)
      MF(Ph[mt][0], Sbh[0]); MF(Ph[mt][1], Sbh[1]);
      MF(Ph[mt][0], Sbl[0]); MF(Ph[mt][1], Sbl[1]);
      MF(Pl[mt][0], Sbh[0]); MF(Pl[mt][1], Sbh[1]);
#undef MF
      accS[mt] = as;
    }

#pragma unroll
    for (int mt = 0; mt < 4; ++mt)
      *(f32x4*)(srow + (size_t)(g + 1) * 64 + mt * 16) = accS[mt];

    if (g + 1 < NGRP - 1) {
      __syncthreads();   // scheduling fence
#pragma unroll
      for (int mt = 0; mt < 4; ++mt)
        *(f32x4*)(&sl[n * 68 + mt * 16 + q * 4]) = accS[mt];
      __syncthreads();
#pragma unroll
      for (int ks = 0; ks < 2; ++ks) {
        f32x4 s0 = *(const f32x4*)(&sl[n * 68 + ks * 32 + q * 8]);
        f32x4 s1 = *(const f32x4*)(&sl[n * 68 + ks * 32 + q * 8 + 4]);
#pragma unroll
        for (int j = 0; j < 4; ++j) {
          u16 hh, ll;
          split2(s0[j], hh, ll); Sbh[ks][j] = (short)hh; Sbl[ks][j] = (short)ll;
          split2(s1[j], hh, ll); Sbh[ks][j + 4] = (short)hh; Sbl[ks][j + 4] = (short)ll;
        }
      }
    }

    ec[0] = en[0]; ec[1] = en[1]; ec[2] = en[2]; ec[3] = en[3];
  }
}

// Main fused kernel: read u + SG, compute y = Wtop@u + A1@S_old, recurrence
// S' = P@S + Wbot@u. P + Wbot in VGPR; Wtop + A1 staged swizzled in LDS.
__global__ void __launch_bounds__(256, 2)
ssm_scan_main(const float* __restrict__ ws, const float* __restrict__ u,
              float* __restrict__ y) {
  __shared__ float SL[4][16 * 68];
  __shared__ __attribute__((aligned(16))) u16 WT[2][4096];   // Wtop hi/lo, swizzled
  __shared__ __attribute__((aligned(16))) u16 A1S[2][4096];  // A1  hi/lo, swizzled
  const int lane = threadIdx.x & 63;
  const int n = lane & 15, q = lane >> 4;
  const int wid = blockIdx.x * 4 + (threadIdx.x >> 6);
  const int R = (wid >> 5) * 16;
  const int g = wid & 31;
  float* sl = SL[threadIdx.x >> 6];

  // stage Wtop + A1 into LDS (swizzled)
  {
    const u16* whg  = (const u16*)(ws + WS_WH);
    const u16* wlg  = (const u16*)(ws + WS_WL);
    const u16* a1hg = (const u16*)(ws + WS_A1H);
    const u16* a1lg = (const u16*)(ws + WS_A1L);
    for (int e = threadIdx.x; e < 4096; e += 256) {
      const int s = swz(e >> 6, e & 63);
      WT[0][s]  = whg[e];  WT[1][s]  = wlg[e];
      A1S[0][s] = a1hg[e]; A1S[1][s] = a1lg[e];
    }
  }

  const u16* ph = (const u16*)(ws + WS_PH);
  const u16* pl = (const u16*)(ws + WS_PL);
  const u16* wh = (const u16*)(ws + WS_WH);
  const u16* wl = (const u16*)(ws + WS_WL);
  bf16x8 Ph[4][2], Pl[4][2], Wbh[4][2], Wbl[4][2];
#pragma unroll
  for (int mt = 0; mt < 4; ++mt)
#pragma unroll
    for (int ks = 0; ks < 2; ++ks) {
      const int off  = (mt * 16 + n) * 64 + ks * 32 + q * 8;
      const int offb = off + 64 * 64;
      Ph[mt][ks]  = *(const bf16x8*)(ph + off);
      Pl[mt][ks]  = *(const bf16x8*)(pl + off);
      Wbh[mt][ks] = *(const bf16x8*)(wh + offb);
      Wbl[mt][ks] = *(const bf16x8*)(wl + offb);
    }

  // S init from sg_g
  bf16x8 Sbh[2], Sbl[2];
  {
    const float* sgp = ws + WS_SG + ((size_t)(R + n) * NGRP + g) * 64;
#pragma unroll
    for (int ks = 0; ks < 2; ++ks) {
      f32x4 s0 = *(const f32x4*)(sgp + ks * 32 + q * 8);
      f32x4 s1 = *(const f32x4*)(sgp + ks * 32 + q * 8 + 4);
#pragma unroll
      for (int j = 0; j < 4; ++j) {
        u16 hh, ll;
        split2(s0[j], hh, ll); Sbh[ks][j] = (short)hh; Sbl[ks][j] = (short)ll;
        split2(s1[j], hh, ll); Sbh[ks][j + 4] = (short)hh; Sbl[ks][j + 4] = (short)ll;
      }
    }
  }

  const int cb = g * GLEN;
  const float* ub = u + (size_t)(R + n) * LSEQ + cb * 64 + q * 8;
  float*     yrow = y + (size_t)(R + n) * LSEQ + q * 4;

  f32x4 f0 = *(const f32x4*)(ub);
  f32x4 f1 = *(const f32x4*)(ub + 4);
  f32x4 f2 = *(const f32x4*)(ub + 32);
  f32x4 f3 = *(const f32x4*)(ub + 36);

  __syncthreads();   // staging visible

  for (int c8 = 0; c8 < GLEN; ++c8) {
    const int c = cb + c8;
    bf16x8 ubh[2], ubl[2];
    {
      float xs0[8] = {f0[0], f0[1], f0[2], f0[3], f1[0], f1[1], f1[2], f1[3]};
      float xs1[8] = {f2[0], f2[1], f2[2], f2[3], f3[0], f3[1], f3[2], f3[3]};
#pragma unroll
      for (int j = 0; j < 8; ++j) {
        u16 hh, ll;
        split2(xs0[j], hh, ll); ubh[0][j] = (short)hh; ubl[0][j] = (short)ll;
        split2(xs1[j], hh, ll); ubh[1][j] = (short)hh; ubl[1][j] = (short)ll;
      }
    }
    const int cn = (c8 + 1 < GLEN) ? (c8 + 1) : c8;
    const float* nb = ub + cn * 64;
    f0 = *(const f32x4*)(nb);
    f1 = *(const f32x4*)(nb + 4);
    f2 = *(const f32x4*)(nb + 32);
    f3 = *(const f32x4*)(nb + 36);

    // accY = Wtop@u + A1@S_old   (frags streamed from LDS)
#pragma unroll
    for (int mt = 0; mt < 4; ++mt) {
      f32x4 ay = {0.f, 0.f, 0.f, 0.f};
      const int o0 = swz(mt * 16 + n, q * 8);
      const int o1 = swz(mt * 16 + n, 32 + q * 8);
      bf16x8 th0 = *(const bf16x8*)(&WT[0][o0]);
      bf16x8 th1 = *(const bf16x8*)(&WT[0][o1]);
      bf16x8 tl0 = *(const bf16x8*)(&WT[1][o0]);
      bf16x8 tl1 = *(const bf16x8*)(&WT[1][o1]);
#define MF(a, b) ay = __builtin_amdgcn_mfma_f32_16x16x32_bf16(a, b, ay, 0, 0, 0)
      MF(th0, ubh[0]); MF(th1, ubh[1]);
      MF(th0, ubl[0]); MF(th1, ubl[1]);
      MF(tl0, ubh[0]); MF(tl1, ubh[1]);
      bf16x8 ah0 = *(const bf16x8*)(&A1S[0][o0]);
      bf16x8 ah1 = *(const bf16x8*)(&A1S[0][o1]);
      bf16x8 al0 = *(const bf16x8*)(&A1S[1][o0]);
      bf16x8 al1 = *(const bf16x8*)(&A1S[1][o1]);
      MF(ah0, Sbh[0]); MF(ah1, Sbh[1]);
      MF(ah0, Sbl[0]); MF(ah1, Sbl[1]);
      MF(al0, Sbh[0]); MF(al1, Sbh[1]);
#undef MF
      *(f32x4*)(yrow + (size_t)c * 64 + mt * 16) = ay;
    }

    // S' = P@S + v  (skip on superchunk-final chunk: S' unused)
    if (c8 + 1 < GLEN) {
      f32x4 accS[4];
#pragma unroll
      for (int mt = 0; mt < 4; ++mt) {
        f32x4 as = {0.f, 0.f, 0.f, 0.f};
#define MF(a, b) as = __builtin_amdgcn_mfma_f32_16x16x32_bf16(a, b, as, 0, 0, 0)
        MF(Wbh[mt][0], ubh[0]); MF(Wbh[mt][1], ubh[1]);    // v  (identical order
        MF(Wbh[mt][0], ubl[0]); MF(Wbh[mt][1], ubl[1]);    //    to ssm_scan_e)
        MF(Wbl[mt][0], ubh[0]); MF(Wbl[mt][1], ubh[1]);
        MF(Ph[mt][0], Sbh[0]);  MF(Ph[mt][1], Sbh[1]);
        MF(Ph[mt][0], Sbl[0]);  MF(Ph[mt][1], Sbl[1]);
        MF(Pl[mt][0], Sbh[0]);  MF(Pl[mt][1], Sbh[1]);
#undef MF
        accS[mt] = as;
      }
      __syncthreads();   // scheduling fence (round-6 lesson)
#pragma unroll
      for (int mt = 0; mt < 4; ++mt)
        *(f32x4*)(&sl[n * 68 + mt * 16 + q * 4]) = accS[mt];
      __syncthreads();
#pragma unroll
      for (int ks = 0; ks < 2; ++ks) {
        f32x4 s0 = *(const f32x4*)(&sl[n * 68 + ks * 32 + q * 8]);
        f32x4 s1 = *(const f32x4*)(&sl[n * 68 + ks * 32 + q * 8 + 4]);
#pragma unroll
        for (int j = 0; j < 4; ++j) {
          u16 hh, ll;
          split2(s0[j], hh, ll); Sbh[ks][j] = (short)hh; Sbl[ks][j] = (short)ll;
          split2(s1[j], hh, ll); Sbh[ks][j + 4] = (short)hh; Sbl[ks][j + 4] = (short)ll;
        }
      }
    }
  }
}

extern "C" void kernel_launch(void* const* d_in, const int* in_sizes, int n_in,
                              void* d_out, int out_size, void* d_ws, size_t ws_size,
                              hipStream_t stream) {
  const float* u  = (const float*)d_in[0];
  const float* A  = (const float*)d_in[1];
  const float* B  = (const float*)d_in[2];
  const float* C  = (const float*)d_in[3];
  const float* D  = (const float*)d_in[4];
  const float* ls = (const float*)d_in[5];
  float* ws  = (float*)d_ws;
  float* out = (float*)d_out;

  ssm_pre<<<dim3(1), dim3(1024), 0, stream>>>(A, B, C, D, ls, ws);
  ssm_scan_e<<<dim3(1024), dim3(256), 0, stream>>>(ws, u);
  ssm_scan_sg<<<dim3(32), dim3(256), 0, stream>>>(ws);
  ssm_scan_main<<<dim3(1024), dim3(256), 0, stream>>>(ws, u, out);
}

// Round 8
// 207.281 us; speedup vs baseline: 1.4609x; 1.2099x over previous
//
#include <hip/hip_runtime.h>
#include <math.h>

#define LSEQ   8192
#define CHUNK  64
#define NCHUNK 128
#define NBATCH 2048
#define NGRP   16      /* superchunks */
#define GLEN   8       /* chunks per superchunk: NGRP*GLEN == NCHUNK */

// ws float layout: E and SG live in the dead v-slot [0, T0); tables at T0+.
#define WS_E   0                            /* NBATCH*NGRP*64 floats */
#define WS_SG  (NBATCH * NGRP * 64)
#define T0     (NBATCH * NCHUNK * 64)
#define WS_WH  (T0 + 8256)    /* 4096 floats = 8192 bf16: W hi, row-major 128x64 */
#define WS_WL  (T0 + 12352)
#define WS_PH  (T0 + 16448)   /* P hi, 64x64, cols sigma^-1-permuted */
#define WS_PL  (T0 + 18496)
#define WS_A1H (T0 + 20544)   /* A1 hi, cols permuted */
#define WS_A1L (T0 + 22592)
#define WS_PGH (T0 + 24640)   /* P^GLEN hi, cols permuted */
#define WS_PGL (T0 + 26688)

typedef short bf16x8 __attribute__((ext_vector_type(8)));
typedef float f32x4  __attribute__((ext_vector_type(4)));
typedef unsigned short u16;

__device__ __forceinline__ u16 bf16rne(float x) {
  unsigned b = __builtin_bit_cast(unsigned, x);
  return (u16)((b + 0x7fffu + ((b >> 16) & 1u)) >> 16);
}
__device__ __forceinline__ float bf2f(u16 h) {
  return __builtin_bit_cast(float, ((unsigned)h) << 16);
}
__device__ __forceinline__ void split2(float x, u16& h, u16& l) {
  h = bf16rne(x);
  l = bf16rne(x - bf2f(h));
}
__device__ __forceinline__ void split3(float x, u16& h, u16& m, u16& l) {
  h = bf16rne(x);
  float r = x - bf2f(h);
  m = bf16rne(r);
  r -= bf2f(m);
  l = bf16rne(r);
}

// State-basis permutation sigma: D-layout slot (mt,q,j) <-> B-frag slot
// (ks=mt>>1, jj=4(mt&1)+j). Tables that CONTRACT with S get columns
// permuted by sigma^-1 so the D-output registers feed the next MFMA's
// B-operand directly (no relayout).
__device__ __forceinline__ int sinv(int c) {
  return (c & 0x23) | ((c & 4) << 2) | ((c & 0x18) >> 1);
}

// XOR swizzle on 8-col groups: kills the stride-128B same-bank pattern for
// ds_read_b128 fragment reads (G4/T2).
__device__ __forceinline__ int swz(int r, int c) {
  return r * 64 + (c ^ ((r & 7) << 3));
}
__device__ __forceinline__ float tri_get(const u16* p, int r, int c) {
  const int e = swz(r, c);
  return bf2f(p[e]) + bf2f(p[4096 + e]) + bf2f(p[8192 + e]);
}

// ---------------- pre: MFMA triple-bf16 64x64 matmuls (round-4, verified) ----
__device__ __forceinline__ void mfma_tile3(
    const u16* __restrict__ A3, const u16* __restrict__ B3, u16* __restrict__ D3,
    int mt, int nt, int aShift,
    const u16* add1, const u16* add2, int addI, int rLo, int rHi) {
  const int lane = threadIdx.x & 63;
  const int n = lane & 15, q = lane >> 4;
  int ar = mt * 16 + n - aShift;
  ar = ar < 0 ? 0 : (ar > 63 ? 63 : ar);
  const int bc = nt * 16 + n;
  bf16x8 ah[2], am[2], al[2], bh[2], bm[2], bl[2];
#pragma unroll
  for (int ks = 0; ks < 2; ++ks) {
    const int ao = swz(ar, ks * 32 + q * 8);
    const int bo = swz(bc, ks * 32 + q * 8);
    ah[ks] = *(const bf16x8*)(A3 + ao);
    am[ks] = *(const bf16x8*)(A3 + 4096 + ao);
    al[ks] = *(const bf16x8*)(A3 + 8192 + ao);
    bh[ks] = *(const bf16x8*)(B3 + bo);
    bm[ks] = *(const bf16x8*)(B3 + 4096 + bo);
    bl[ks] = *(const bf16x8*)(B3 + 8192 + bo);
  }
  f32x4 acc = {0.f, 0.f, 0.f, 0.f};
#define MF(a, b) acc = __builtin_amdgcn_mfma_f32_16x16x32_bf16(a, b, acc, 0, 0, 0)
  MF(ah[0], bh[0]); MF(ah[1], bh[1]);
  MF(ah[0], bm[0]); MF(ah[1], bm[1]);
  MF(am[0], bh[0]); MF(am[1], bh[1]);
  MF(ah[0], bl[0]); MF(ah[1], bl[1]);
  MF(am[0], bm[0]); MF(am[1], bm[1]);
  MF(al[0], bh[0]); MF(al[1], bh[1]);
#undef MF
#pragma unroll
  for (int j = 0; j < 4; ++j) {
    const int i = mt * 16 + q * 4 + j, c = nt * 16 + n;
    float v = acc[j];
    if (add1) v += tri_get(add1, i, c);
    if (add2) v += tri_get(add2, i, c);
    if (addI && i == c) v += 1.f;
    if (i >= rLo && i < rHi) {
      u16 h3, m3, l3; split3(v, h3, m3, l3);
      const int e = swz(i, c);
      D3[e] = h3; D3[4096 + e] = m3; D3[8192 + e] = l3;
    }
  }
}

__device__ __forceinline__ void pair_phase(
    const u16* Pf, const u16* Qt, u16* Fn, u16* Tn,
    const u16* addF1, const u16* addT1, int addI) {
  __syncthreads();
  const int w = threadIdx.x >> 6;
#pragma unroll
  for (int tix = w; tix < 32; tix += 16) {
    if (tix < 16) mfma_tile3(Pf, Qt, Fn, tix >> 2, tix & 3, 0, addF1, 0, addI, 0, 64);
    else { const int s = tix - 16; mfma_tile3(Qt, Pf, Tn, s >> 2, s & 3, 0, addT1, 0, addI, 0, 64); }
  }
}
__device__ __forceinline__ void single_phase(
    const u16* A3, const u16* B3, u16* D3,
    const u16* add1, const u16* add2, int addI) {
  __syncthreads();
  const int w = threadIdx.x >> 6;
  mfma_tile3(A3, B3, D3, w >> 2, w & 3, 0, add1, add2, addI, 0, 64);
}

__global__ void __launch_bounds__(1024)
ssm_pre(const float* __restrict__ Ag, const float* __restrict__ Bg,
        const float* __restrict__ Cg, const float* __restrict__ Dg,
        const float* __restrict__ lsg, float* __restrict__ ws) {
  __shared__ __attribute__((aligned(16))) u16 TRI[6][3 * 4096];
  __shared__ float Kl[64];
  u16* tri0 = TRI[0]; u16* tri1 = TRI[1]; u16* tri2 = TRI[2];
  u16* tri3 = TRI[3]; u16* tri4 = TRI[4]; u16* tri5 = TRI[5];

  const int t = threadIdx.x;
  const int w = t >> 6;
  const float step = expf(lsg[0]);
  const float hstep = 0.5f * step;
  const float D0 = Dg[0];

  float* Xf = (float*)tri2;
  for (int e = t; e < 4096; e += 1024) {
    const float x = hstep * Ag[e];
    Xf[e] = x;
    u16 h3, m3, l3; split3(x, h3, m3, l3);
    const int s = swz(e >> 6, e & 63);
    tri0[s] = h3; tri0[4096 + s] = m3; tri0[8192 + s] = l3;
  }
  __syncthreads();
  for (int e = t; e < 4096; e += 1024) {
    const int r = e >> 6, c = e & 63;
    const float x = Xf[c * 64 + r];
    u16 h3, m3, l3; split3(x, h3, m3, l3);
    const int s = swz(r, c);
    tri1[s] = h3; tri1[4096 + s] = m3; tri1[8192 + s] = l3;
  }
  pair_phase(tri0, tri1, tri2, tri3, 0, 0, 0);          // X2
  pair_phase(tri2, tri3, tri4, tri5, 0, 0, 0);          // X4
  single_phase(tri4, tri3, tri0, tri4, tri2, 1);        // T1
  single_phase(tri3, tri4, tri2, tri3, tri5, 1);        // T1T
  pair_phase(tri0, tri1, tri3, tri5, tri0, tri2, 0);    // BL / BLT
  pair_phase(tri3, tri1, tri4, tri2, tri3, tri5, 0);    // Ab / AbT

  __syncthreads();
  if (t < 64) {
    float acc = 0.f;
    for (int m = 0; m < 64; ++m) acc += tri_get(tri3, t, m) * Bg[m];  // BL row t
    const float bb = step * acc;
    u16 h3, m3, l3; split3(bb, h3, m3, l3);
    const int s = swz(0, t);
    tri0[s] = h3; tri0[4096 + s] = m3; tri0[8192 + s] = l3;
  } else if (t < 128) {
    const int r = t - 64;
    float acc = 0.f;
    for (int m = 0; m < 64; ++m) acc += tri_get(tri2, r, m) * Cg[m];  // AbT row r
    u16 h3, m3, l3; split3(acc, h3, m3, l3);
    const int s = swz(0, r);
    tri1[s] = h3; tri1[4096 + s] = m3; tri1[8192 + s] = l3;
  }

  u16 *curF = tri4, *curT = tri2, *nxtF = tri3, *nxtT = tri5;
  for (int k = 1; k <= 32; k <<= 1) {
    __syncthreads();
    const int mtLo = k >> 4, mtHi = (2 * k - 1) >> 4;
    const int cnt = (mtHi - mtLo + 1) * 4;
    const int total = 32 + 2 * cnt;
    for (int tix = w; tix < total; tix += 16) {
      if (tix < 16) {
        mfma_tile3(curF, curT, nxtF, tix >> 2, tix & 3, 0, 0, 0, 0, 0, 64);
      } else if (tix < 32) {
        const int s = tix - 16;
        mfma_tile3(curT, curF, nxtT, s >> 2, s & 3, 0, 0, 0, 0, 0, 64);
      } else if (tix < 32 + cnt) {
        const int s = tix - 32;
        mfma_tile3(tri0, curF, tri0, mtLo + (s >> 2), s & 3, k, 0, 0, 0, k, 2 * k);
      } else {
        const int s = tix - 32 - cnt;
        mfma_tile3(tri1, curT, tri1, mtLo + (s >> 2), s & 3, k, 0, 0, 0, k, 2 * k);
      }
    }
    u16* tmp;
    tmp = curF; curF = nxtF; nxtF = tmp;
    tmp = curT; curT = nxtT; nxtT = tmp;
  }

  __syncthreads();
  u16* ph  = (u16*)(ws + WS_PH);
  u16* pl  = (u16*)(ws + WS_PL);
  u16* a1h = (u16*)(ws + WS_A1H);
  u16* a1l = (u16*)(ws + WS_A1L);
  u16* pgh = (u16*)(ws + WS_PGH);
  u16* pgl = (u16*)(ws + WS_PGL);
  // P table: columns sigma^-1-permuted (P contracts with S)
  for (int e = t; e < 4096; e += 1024) {
    const int r = e >> 6, c = e & 63;
    const float x = tri_get(curF, r, sinv(c));
    u16 hh, ll; split2(x, hh, ll); ph[e] = hh; pl[e] = ll;
  }
  // tail: P^2, P^4, P^8 = P^GLEN (GLEN==8) — three pair squarings
  for (int r2 = 0; r2 < 3; ++r2) {
    pair_phase(curF, curT, nxtF, nxtT, 0, 0, 0);
    u16* tmp;
    tmp = curF; curF = nxtF; nxtF = tmp;
    tmp = curT; curT = nxtT; nxtT = tmp;
  }
  __syncthreads();
  // P8 + A1 tables (both contract with S -> columns permuted)
  for (int e = t; e < 4096; e += 1024) {
    const int r = e >> 6, c = e & 63, ci = sinv(c);
    float x = tri_get(curF, r, ci);
    u16 hh, ll; split2(x, hh, ll); pgh[e] = hh; pgl[e] = ll;
    const float a1v = tri_get(tri1, r, ci);
    split2(a1v, hh, ll); a1h[e] = hh; a1l[e] = ll;
  }
  if (t < 64) {
    float acc = 0.f;
    for (int m = 0; m < 64; ++m) acc += Cg[m] * tri_get(tri0, t, m);
    Kl[t] = acc;
  }
  __syncthreads();
  u16* wh = (u16*)(ws + WS_WH);
  u16* wl = (u16*)(ws + WS_WL);
  for (int e = t; e < 8192; e += 1024) {
    const int i = e >> 6, j = e & 63;
    float wv;
    if (i < 64) wv = ((i >= j) ? Kl[i - j] : 0.f) + ((i == j) ? D0 : 0.f);
    else        wv = tri_get(tri0, 63 - j, i - 64);   // gB[m][jj] = gBT[jj][m]
    u16 hh, ll; split2(wv, hh, ll);
    wh[e] = hh;
    wl[e] = ll;
  }
}

// -------- fused scan, NGRP=16 x GLEN=8 (round-5 proven geometry) -------------
// State hand-off is now register-direct: D-output acc[mt][j] IS the next
// B-frag elem (ks=mt>>1, jj=4(mt&1)+j) because P/A1/P8 columns are
// sigma^-1-permuted in pre. No LDS, no barriers in the scan loops.
// sched_barrier(0) at loop end prevents cross-iteration pipelining (the
// round-6 spill mechanism).

__device__ __forceinline__ void acc_to_bfrag(const f32x4* accS,
                                             bf16x8* Sbh, bf16x8* Sbl) {
#pragma unroll
  for (int mt = 0; mt < 4; ++mt)
#pragma unroll
    for (int j = 0; j < 4; ++j) {
      u16 hh, ll; split2(accS[mt][j], hh, ll);
      Sbh[mt >> 1][(mt & 1) * 4 + j] = (short)hh;
      Sbl[mt >> 1][(mt & 1) * 4 + j] = (short)ll;
    }
}

// E-kernel: read u, local scan from s=0 -> E_g (E stored in phys row order).
__global__ void __launch_bounds__(256, 2)
ssm_scan_e(float* __restrict__ ws, const float* __restrict__ u) {
  const int lane = threadIdx.x & 63;
  const int n = lane & 15, q = lane >> 4;
  const int wid = blockIdx.x * 4 + (threadIdx.x >> 6);
  const int R = (wid >> 4) * 16;
  const int g = wid & 15;

  const u16* ph = (const u16*)(ws + WS_PH);
  const u16* pl = (const u16*)(ws + WS_PL);
  const u16* wh = (const u16*)(ws + WS_WH);
  const u16* wl = (const u16*)(ws + WS_WL);
  bf16x8 Ph[4][2], Pl[4][2], Wbh[4][2], Wbl[4][2];
#pragma unroll
  for (int mt = 0; mt < 4; ++mt)
#pragma unroll
    for (int ks = 0; ks < 2; ++ks) {
      const int off  = (mt * 16 + n) * 64 + ks * 32 + q * 8;
      const int offb = off + 64 * 64;             // Wbot rows 64..127
      Ph[mt][ks]  = *(const bf16x8*)(ph + off);
      Pl[mt][ks]  = *(const bf16x8*)(pl + off);
      Wbh[mt][ks] = *(const bf16x8*)(wh + offb);
      Wbl[mt][ks] = *(const bf16x8*)(wl + offb);
    }

  bf16x8 Sbh[2], Sbl[2];
#pragma unroll
  for (int ks = 0; ks < 2; ++ks)
#pragma unroll
    for (int j = 0; j < 8; ++j) { Sbh[ks][j] = 0; Sbl[ks][j] = 0; }

  const int cb = g * GLEN;
  const float* ub = u + (size_t)(R + n) * LSEQ + cb * 64 + q * 8;

  f32x4 f0 = *(const f32x4*)(ub);
  f32x4 f1 = *(const f32x4*)(ub + 4);
  f32x4 f2 = *(const f32x4*)(ub + 32);
  f32x4 f3 = *(const f32x4*)(ub + 36);

  for (int c8 = 0; c8 < GLEN; ++c8) {
    bf16x8 ubh[2], ubl[2];
    {
      float xs0[8] = {f0[0], f0[1], f0[2], f0[3], f1[0], f1[1], f1[2], f1[3]};
      float xs1[8] = {f2[0], f2[1], f2[2], f2[3], f3[0], f3[1], f3[2], f3[3]};
#pragma unroll
      for (int j = 0; j < 8; ++j) {
        u16 hh, ll;
        split2(xs0[j], hh, ll); ubh[0][j] = (short)hh; ubl[0][j] = (short)ll;
        split2(xs1[j], hh, ll); ubh[1][j] = (short)hh; ubl[1][j] = (short)ll;
      }
    }
    const int cn = (c8 + 1 < GLEN) ? (c8 + 1) : c8;
    const float* nb = ub + cn * 64;
    f0 = *(const f32x4*)(nb);
    f1 = *(const f32x4*)(nb + 4);
    f2 = *(const f32x4*)(nb + 32);
    f3 = *(const f32x4*)(nb + 36);

    f32x4 accS[4];
#pragma unroll
    for (int mt = 0; mt < 4; ++mt) {
      f32x4 as = {0.f, 0.f, 0.f, 0.f};
#define MF(a, b) as = __builtin_amdgcn_mfma_f32_16x16x32_bf16(a, b, as, 0, 0, 0)
      MF(Wbh[mt][0], ubh[0]); MF(Wbh[mt][1], ubh[1]);      // v = Wbot@u
      MF(Wbh[mt][0], ubl[0]); MF(Wbh[mt][1], ubl[1]);
      MF(Wbl[mt][0], ubh[0]); MF(Wbl[mt][1], ubh[1]);
      MF(Ph[mt][0], Sbh[0]);  MF(Ph[mt][1], Sbh[1]);       // + P~@S
      MF(Ph[mt][0], Sbl[0]);  MF(Ph[mt][1], Sbl[1]);
      MF(Pl[mt][0], Sbh[0]);  MF(Pl[mt][1], Sbh[1]);
#undef MF
      accS[mt] = as;
    }

    if (c8 + 1 < GLEN) {
      acc_to_bfrag(accS, Sbh, Sbl);      // register-direct hand-off
    } else {
      float* eb = ws + WS_E + ((size_t)(R + n) * NGRP + g) * 64 + q * 4;
#pragma unroll
      for (int mt = 0; mt < 4; ++mt)
        *(f32x4*)(eb + mt * 16) = accS[mt];
    }
    __builtin_amdgcn_sched_barrier(0);   // no cross-iteration pipelining
  }
}

// sigma-kernel: per row-group boundary scan sg_{g+1} = P8~@sg_g + E_g.
__global__ void __launch_bounds__(256, 2)
ssm_scan_sg(float* __restrict__ ws) {
  const int lane = threadIdx.x & 63;
  const int n = lane & 15, q = lane >> 4;
  const int wid = blockIdx.x * 4 + (threadIdx.x >> 6);
  const int R = wid * 16;

  const u16* pgh = (const u16*)(ws + WS_PGH);
  const u16* pgl = (const u16*)(ws + WS_PGL);
  bf16x8 Ph[4][2], Pl[4][2];
#pragma unroll
  for (int mt = 0; mt < 4; ++mt)
#pragma unroll
    for (int ks = 0; ks < 2; ++ks) {
      int off = (mt * 16 + n) * 64 + ks * 32 + q * 8;
      Ph[mt][ks] = *(const bf16x8*)(pgh + off);
      Pl[mt][ks] = *(const bf16x8*)(pgl + off);
    }

  bf16x8 Sbh[2], Sbl[2];
#pragma unroll
  for (int ks = 0; ks < 2; ++ks)
#pragma unroll
    for (int j = 0; j < 8; ++j) { Sbh[ks][j] = 0; Sbl[ks][j] = 0; }

  const float* erow = ws + WS_E + ((size_t)(R + n) * NGRP) * 64 + q * 4;
  float*       srow = ws + WS_SG + ((size_t)(R + n) * NGRP) * 64 + q * 4;

  {
    f32x4 z = {0.f, 0.f, 0.f, 0.f};
#pragma unroll
    for (int mt = 0; mt < 4; ++mt) *(f32x4*)(srow + mt * 16) = z;
  }

  f32x4 ec[4];
#pragma unroll
  for (int mt = 0; mt < 4; ++mt) ec[mt] = *(const f32x4*)(erow + mt * 16);

  for (int g = 0; g < NGRP - 1; ++g) {
    const int gn = (g + 1 < NGRP - 1) ? (g + 1) : g;
    f32x4 en[4];
#pragma unroll
    for (int mt = 0; mt < 4; ++mt)
      en[mt] = *(const f32x4*)(erow + (size_t)gn * 64 + mt * 16);

    f32x4 accS[4];
#pragma unroll
    for (int mt = 0; mt < 4; ++mt) {
      f32x4 as = ec[mt];
#define MF(a, b) as = __builtin_amdgcn_mfma_f32_16x16x32_bf16(a, b, as, 0, 0, 0)
      MF(Ph[mt][0], Sbh[0]); MF(Ph[mt][1], Sbh[1]);
      MF(Ph[mt][0], Sbl[0]); MF(Ph[mt][1], Sbl[1]);
      MF(Pl[mt][0], Sbh[0]); MF(Pl[mt][1], Sbh[1]);
#undef MF
      accS[mt] = as;
    }

#pragma unroll
    for (int mt = 0; mt < 4; ++mt)
      *(f32x4*)(srow + (size_t)(g + 1) * 64 + mt * 16) = accS[mt];

    if (g + 1 < NGRP - 1) acc_to_bfrag(accS, Sbh, Sbl);
    __builtin_amdgcn_sched_barrier(0);

    ec[0] = en[0]; ec[1] = en[1]; ec[2] = en[2]; ec[3] = en[3];
  }
}

// Main fused kernel: read u + SG, y = Wtop@u + A1~@S_old, S' = P~@S + Wbot@u.
// P~ + Wbot in VGPR; Wtop + A1~ staged swizzled in LDS (32 KB total now).
__global__ void __launch_bounds__(256, 2)
ssm_scan_main(const float* __restrict__ ws, const float* __restrict__ u,
              float* __restrict__ y) {
  __shared__ __attribute__((aligned(16))) u16 WT[2][4096];   // Wtop hi/lo, swizzled
  __shared__ __attribute__((aligned(16))) u16 A1S[2][4096];  // A1~ hi/lo, swizzled
  const int lane = threadIdx.x & 63;
  const int n = lane & 15, q = lane >> 4;
  const int wid = blockIdx.x * 4 + (threadIdx.x >> 6);
  const int R = (wid >> 4) * 16;
  const int g = wid & 15;

  // stage Wtop + A1~ into LDS (swizzled)
  {
    const u16* whg  = (const u16*)(ws + WS_WH);
    const u16* wlg  = (const u16*)(ws + WS_WL);
    const u16* a1hg = (const u16*)(ws + WS_A1H);
    const u16* a1lg = (const u16*)(ws + WS_A1L);
    for (int e = threadIdx.x; e < 4096; e += 256) {
      const int s = swz(e >> 6, e & 63);
      WT[0][s]  = whg[e];  WT[1][s]  = wlg[e];
      A1S[0][s] = a1hg[e]; A1S[1][s] = a1lg[e];
    }
  }

  const u16* ph = (const u16*)(ws + WS_PH);
  const u16* pl = (const u16*)(ws + WS_PL);
  const u16* wh = (const u16*)(ws + WS_WH);
  const u16* wl = (const u16*)(ws + WS_WL);
  bf16x8 Ph[4][2], Pl[4][2], Wbh[4][2], Wbl[4][2];
#pragma unroll
  for (int mt = 0; mt < 4; ++mt)
#pragma unroll
    for (int ks = 0; ks < 2; ++ks) {
      const int off  = (mt * 16 + n) * 64 + ks * 32 + q * 8;
      const int offb = off + 64 * 64;
      Ph[mt][ks]  = *(const bf16x8*)(ph + off);
      Pl[mt][ks]  = *(const bf16x8*)(pl + off);
      Wbh[mt][ks] = *(const bf16x8*)(wh + offb);
      Wbl[mt][ks] = *(const bf16x8*)(wl + offb);
    }

  // S init from sg_g (phys order in memory; B-frag slot (ks,jj) needs
  // phys index 16*(2ks+(jj>>2)) + 4q + (jj&3))
  bf16x8 Sbh[2], Sbl[2];
  {
    const float* sgp = ws + WS_SG + ((size_t)(R + n) * NGRP + g) * 64;
#pragma unroll
    for (int ks = 0; ks < 2; ++ks) {
      f32x4 s0 = *(const f32x4*)(sgp + ks * 32 + q * 4);        // jj=0..3
      f32x4 s1 = *(const f32x4*)(sgp + ks * 32 + 16 + q * 4);   // jj=4..7
#pragma unroll
      for (int j = 0; j < 4; ++j) {
        u16 hh, ll;
        split2(s0[j], hh, ll); Sbh[ks][j] = (short)hh; Sbl[ks][j] = (short)ll;
        split2(s1[j], hh, ll); Sbh[ks][j + 4] = (short)hh; Sbl[ks][j + 4] = (short)ll;
      }
    }
  }

  const int cb = g * GLEN;
  const float* ub = u + (size_t)(R + n) * LSEQ + cb * 64 + q * 8;
  float*     yrow = y + (size_t)(R + n) * LSEQ + q * 4;

  f32x4 f0 = *(const f32x4*)(ub);
  f32x4 f1 = *(const f32x4*)(ub + 4);
  f32x4 f2 = *(const f32x4*)(ub + 32);
  f32x4 f3 = *(const f32x4*)(ub + 36);

  __syncthreads();   // staging visible

  for (int c8 = 0; c8 < GLEN; ++c8) {
    const int c = cb + c8;
    bf16x8 ubh[2], ubl[2];
    {
      float xs0[8] = {f0[0], f0[1], f0[2], f0[3], f1[0], f1[1], f1[2], f1[3]};
      float xs1[8] = {f2[0], f2[1], f2[2], f2[3], f3[0], f3[1], f3[2], f3[3]};
#pragma unroll
      for (int j = 0; j < 8; ++j) {
        u16 hh, ll;
        split2(xs0[j], hh, ll); ubh[0][j] = (short)hh; ubl[0][j] = (short)ll;
        split2(xs1[j], hh, ll); ubh[1][j] = (short)hh; ubl[1][j] = (short)ll;
      }
    }
    const int cn = (c8 + 1 < GLEN) ? (c8 + 1) : c8;
    const float* nb = ub + cn * 64;
    f0 = *(const f32x4*)(nb);
    f1 = *(const f32x4*)(nb + 4);
    f2 = *(const f32x4*)(nb + 32);
    f3 = *(const f32x4*)(nb + 36);

    // accY = Wtop@u + A1~@S_old   (frags streamed from LDS)
#pragma unroll
    for (int mt = 0; mt < 4; ++mt) {
      f32x4 ay = {0.f, 0.f, 0.f, 0.f};
      const int o0 = swz(mt * 16 + n, q * 8);
      const int o1 = swz(mt * 16 + n, 32 + q * 8);
      bf16x8 th0 = *(const bf16x8*)(&WT[0][o0]);
      bf16x8 th1 = *(const bf16x8*)(&WT[0][o1]);
      bf16x8 tl0 = *(const bf16x8*)(&WT[1][o0]);
      bf16x8 tl1 = *(const bf16x8*)(&WT[1][o1]);
#define MF(a, b) ay = __builtin_amdgcn_mfma_f32_16x16x32_bf16(a, b, ay, 0, 0, 0)
      MF(th0, ubh[0]); MF(th1, ubh[1]);
      MF(th0, ubl[0]); MF(th1, ubl[1]);
      MF(tl0, ubh[0]); MF(tl1, ubh[1]);
      bf16x8 ah0 = *(const bf16x8*)(&A1S[0][o0]);
      bf16x8 ah1 = *(const bf16x8*)(&A1S[0][o1]);
      bf16x8 al0 = *(const bf16x8*)(&A1S[1][o0]);
      bf16x8 al1 = *(const bf16x8*)(&A1S[1][o1]);
      MF(ah0, Sbh[0]); MF(ah1, Sbh[1]);
      MF(ah0, Sbl[0]); MF(ah1, Sbl[1]);
      MF(al0, Sbh[0]); MF(al1, Sbh[1]);
#undef MF
      *(f32x4*)(yrow + (size_t)c * 64 + mt * 16) = ay;
    }

    // S' = P~@S + v  (skip on superchunk-final chunk: S' unused)
    if (c8 + 1 < GLEN) {
      f32x4 accS[4];
#pragma unroll
      for (int mt = 0; mt < 4; ++mt) {
        f32x4 as = {0.f, 0.f, 0.f, 0.f};
#define MF(a, b) as = __builtin_amdgcn_mfma_f32_16x16x32_bf16(a, b, as, 0, 0, 0)
        MF(Wbh[mt][0], ubh[0]); MF(Wbh[mt][1], ubh[1]);    // v  (identical order
        MF(Wbh[mt][0], ubl[0]); MF(Wbh[mt][1], ubl[1]);    //    to ssm_scan_e)
        MF(Wbl[mt][0], ubh[0]); MF(Wbl[mt][1], ubh[1]);
        MF(Ph[mt][0], Sbh[0]);  MF(Ph[mt][1], Sbh[1]);
        MF(Ph[mt][0], Sbl[0]);  MF(Ph[mt][1], Sbl[1]);
        MF(Pl[mt][0], Sbh[0]);  MF(Pl[mt][1], Sbh[1]);
#undef MF
        accS[mt] = as;
      }
      acc_to_bfrag(accS, Sbh, Sbl);      // register-direct hand-off
    }
    __builtin_amdgcn_sched_barrier(0);   // no cross-iteration pipelining
  }
}

extern "C" void kernel_launch(void* const* d_in, const int* in_sizes, int n_in,
                              void* d_out, int out_size, void* d_ws, size_t ws_size,
                              hipStream_t stream) {
  const float* u  = (const float*)d_in[0];
  const float* A  = (const float*)d_in[1];
  const float* B  = (const float*)d_in[2];
  const float* C  = (const float*)d_in[3];
  const float* D  = (const float*)d_in[4];
  const float* ls = (const float*)d_in[5];
  float* ws  = (float*)d_ws;
  float* out = (float*)d_out;

  ssm_pre<<<dim3(1), dim3(1024), 0, stream>>>(A, B, C, D, ls, ws);
  ssm_scan_e<<<dim3(512), dim3(256), 0, stream>>>(ws, u);
  ssm_scan_sg<<<dim3(32), dim3(256), 0, stream>>>(ws);
  ssm_scan_main<<<dim3(512), dim3(256), 0, stream>>>(ws, u, out);
}